// Round 4
// baseline (126.335 us; speedup 1.0000x reference)
//
#include <hip/hip_runtime.h>
#include <math.h>

#define DIM 1024
#define NQ 10
#define NL 4
#define SEQ 512
#define NROWS 4096
#define PRED 96

typedef unsigned short ushort_t;
typedef unsigned int uint_t;
using half8   = __attribute__((ext_vector_type(8))) _Float16;
using float4v = __attribute__((ext_vector_type(4))) float;

__device__ inline uint_t pkh(float a, float b) {
    _Float16 ha = (_Float16)a, hb = (_Float16)b;   // RTE v_cvt_f16_f32
    return (uint_t)(*(ushort_t*)&ha) | ((uint_t)(*(ushort_t*)&hb) << 16);
}

// XOR-ladder layer permutation (GF(2)-linear). Matches R1's verified code.
__device__ inline int permf(int s, int r) {
#pragma unroll
    for (int c = 9; c >= 0; --c) {
        int t = (c + r) % 10;
        s ^= ((s >> (9 - c)) & 1) << (9 - t);
    }
    return s;
}

// ---------------------------------------------------------------------------
// Kernel 0: x (fp32) -> xh (f16), same layout. 8 floats/thread.
// ---------------------------------------------------------------------------
__global__ __launch_bounds__(256)
void convert_x_kernel(const float* __restrict__ x, ushort_t* __restrict__ xh)
{
    int i = (blockIdx.x * 256 + threadIdx.x) * 8;
    float4 a = *(const float4*)(x + i);
    float4 b = *(const float4*)(x + i + 4);
    uint4 o;
    o.x = pkh(a.x, a.y); o.y = pkh(a.z, a.w);
    o.z = pkh(b.x, b.y); o.w = pkh(b.z, b.w);
    *(uint4*)(xh + i) = o;
}

// ---------------------------------------------------------------------------
// Kernel 1: wave-per-column circuit, register-resident, barrier-free core.
// Lane l holds states s = l*16 + r (r=0..15) as float2 P[16].
//   wires 6..9 -> register-local 2x2; wires 0..5 -> __shfl_xor exchange.
//   layer perm -> in-wave LDS gather via linearity: src = perm(l*16)^perm(r).
// Wave j<512: column j of W_in; j==512: bias column -> dr/di (fp32).
// Output j<512: Cjm_r/Cjm_i[j][s] (f16, row-coalesced).
// ---------------------------------------------------------------------------
__global__ __launch_bounds__(256)
void circuit_wave_kernel(const float* __restrict__ Wi, const float* __restrict__ b_in,
                         const float* __restrict__ qw,
                         ushort_t* __restrict__ Cjm_r, ushort_t* __restrict__ Cjm_i,
                         float* __restrict__ dr, float* __restrict__ di)
{
    __shared__ float gm[NL * NQ][8];
    __shared__ float2 scr[4 * 1024];   // 8 KB per wave, wave-private

    const int tid = threadIdx.x;
    const int lane = tid & 63;
    const int wv = tid >> 6;
    const int jorig = blockIdx.x * 4 + wv;
    const bool valid = (jorig <= SEQ);
    const int j = valid ? jorig : SEQ;

    if (tid < NL * NQ) {
        float phi = qw[tid * 3 + 0], theta = qw[tid * 3 + 1], omega = qw[tid * 3 + 2];
        float ch = cosf(theta * 0.5f), sh = sinf(theta * 0.5f);
        float a = 0.5f * (phi + omega), b = 0.5f * (phi - omega);
        float ca = cosf(a), sa = sinf(a);
        float cb = cosf(b), sb = sinf(b);
        gm[tid][0] =  ch * ca;  gm[tid][1] = -ch * sa;   // m00
        gm[tid][2] = -sh * cb;  gm[tid][3] = -sh * sb;   // m01
        gm[tid][4] =  sh * cb;  gm[tid][5] = -sh * sb;   // m10
        gm[tid][6] =  ch * ca;  gm[tid][7] =  ch * sa;   // m11
    }
    __syncthreads();

    float2 P[16];
    if (j < SEQ) {
#pragma unroll
        for (int r = 0; r < 16; ++r)
            P[r] = make_float2(Wi[(size_t)(lane * 16 + r) * SEQ + j], 0.f);
    } else {
#pragma unroll
        for (int r = 0; r < 16; ++r)
            P[r] = make_float2(b_in[lane * 16 + r] + 1e-6f, 0.f);
    }

    float2* wscr = scr + wv * 1024;

#pragma unroll
    for (int l = 0; l < NL; ++l) {
#pragma unroll
        for (int w = 0; w < NQ; ++w) {
            const float* m = gm[l * NQ + w];
            float m00r = m[0], m00i = m[1], m01r = m[2], m01i = m[3];
            float m10r = m[4], m10i = m[5], m11r = m[6], m11i = m[7];
            if (w <= 5) {
                // state bit b = 9-w >= 4  -> lane bit lb = 5-w
                const int lb = 5 - w;
                const int mask = 1 << lb;
                const int myb = (lane >> lb) & 1;
                float cAr = myb ? m11r : m00r, cAi = myb ? m11i : m00i;
                float cQr = myb ? m10r : m01r, cQi = myb ? m10i : m01i;
#pragma unroll
                for (int r = 0; r < 16; ++r) {
                    float ar = P[r].x, ai = P[r].y;
                    float qr_ = __shfl_xor(ar, mask, 64);
                    float qi_ = __shfl_xor(ai, mask, 64);
                    P[r].x = cAr * ar - cAi * ai + cQr * qr_ - cQi * qi_;
                    P[r].y = cAr * ai + cAi * ar + cQr * qi_ + cQi * qr_;
                }
            } else {
                // state bit b = 9-w <= 3 -> register-local pairs
                const int mk = 1 << (9 - w);
#pragma unroll
                for (int r0 = 0; r0 < 16; ++r0) {
                    if (r0 & mk) continue;
                    float2 a0 = P[r0], a1 = P[r0 | mk];
                    float2 n0, n1;
                    n0.x = m00r * a0.x - m00i * a0.y + m01r * a1.x - m01i * a1.y;
                    n0.y = m00r * a0.y + m00i * a0.x + m01r * a1.y + m01i * a1.x;
                    n1.x = m10r * a0.x - m10i * a0.y + m11r * a1.x - m11i * a1.y;
                    n1.y = m10r * a0.y + m10i * a0.x + m11r * a1.y + m11i * a1.x;
                    P[r0] = n0; P[r0 | mk] = n1;
                }
            }
        }
        // layer permutation via wave-private LDS (no block barrier needed:
        // within-wave LDS ops are program-ordered via lgkmcnt)
        const int rr = l % (NQ - 1) + 1;
#pragma unroll
        for (int r = 0; r < 16; ++r) wscr[lane * 16 + r] = P[r];
        int pl = permf(lane << 4, rr);
#pragma unroll
        for (int r = 0; r < 16; ++r) {
            int src = pl ^ permf(r, rr);   // permf(r, rr) folds to a constant
            P[r] = wscr[src];
        }
    }

    if (valid) {
        if (j < SEQ) {
            uint4 o0, o1, p0, p1;
            o0.x = pkh(P[0].x,  P[1].x);  o0.y = pkh(P[2].x,  P[3].x);
            o0.z = pkh(P[4].x,  P[5].x);  o0.w = pkh(P[6].x,  P[7].x);
            o1.x = pkh(P[8].x,  P[9].x);  o1.y = pkh(P[10].x, P[11].x);
            o1.z = pkh(P[12].x, P[13].x); o1.w = pkh(P[14].x, P[15].x);
            p0.x = pkh(P[0].y,  P[1].y);  p0.y = pkh(P[2].y,  P[3].y);
            p0.z = pkh(P[4].y,  P[5].y);  p0.w = pkh(P[6].y,  P[7].y);
            p1.x = pkh(P[8].y,  P[9].y);  p1.y = pkh(P[10].y, P[11].y);
            p1.z = pkh(P[12].y, P[13].y); p1.w = pkh(P[14].y, P[15].y);
            size_t base = (size_t)j * DIM + lane * 16;
            *(uint4*)(Cjm_r + base)     = o0;
            *(uint4*)(Cjm_r + base + 8) = o1;
            *(uint4*)(Cjm_i + base)     = p0;
            *(uint4*)(Cjm_i + base + 8) = p1;
        } else {
#pragma unroll
            for (int r = 0; r < 16; ++r) {
                dr[lane * 16 + r] = P[r].x;
                di[lane * 16 + r] = P[r].y;
            }
        }
    }
}

// ---------------------------------------------------------------------------
// Kernel 2: transpose C from [j][s] (1 MB each) to s-major [s][j] for GEMM.
// 64x64 half tiles; scatter-on-LDS-write, vectorized read+store.
// ---------------------------------------------------------------------------
__global__ __launch_bounds__(256)
void transpose_c_kernel(const ushort_t* __restrict__ in_r, const ushort_t* __restrict__ in_i,
                        ushort_t* __restrict__ out_r, ushort_t* __restrict__ out_i)
{
    __shared__ ushort_t Ts[64][80];   // [s][j], stride 160 B (16-aligned)
    const int tid = threadIdx.x;
    const int j0 = blockIdx.x * 64;
    const int s0 = blockIdx.y * 64;

    for (int a = 0; a < 2; ++a) {
        const ushort_t* in = a ? in_i : in_r;
        ushort_t* out = a ? out_i : out_r;
#pragma unroll
        for (int g = 0; g < 2; ++g) {
            int G = tid + g * 256;
            int jj = G >> 3, ch = G & 7;
            uint4 v = *(const uint4*)(in + (size_t)(j0 + jj) * DIM + s0 + ch * 8);
            const ushort_t* hv = (const ushort_t*)&v;
#pragma unroll
            for (int q = 0; q < 8; ++q) Ts[ch * 8 + q][jj] = hv[q];
        }
        __syncthreads();
#pragma unroll
        for (int g = 0; g < 2; ++g) {
            int G = tid + g * 256;
            int ss = G >> 3, jc = G & 7;
            uint4 v = *(const uint4*)(&Ts[ss][jc * 8]);
            *(uint4*)(out + (size_t)(s0 + ss) * SEQ + j0 + jc * 8) = v;
        }
        __syncthreads();
    }
}

// ---------------------------------------------------------------------------
// Kernel 3: fused f16-MFMA GEMM + probs + signed partial reduction.
// Identical structure/indexing to the R3-verified kernel, but A comes
// pre-converted (xh f16) -> staging is a pure uint4 pass-through.
// ---------------------------------------------------------------------------
#define GBM 128
#define GBNC 64
#define GBK 32
#define LDA 40
#define LDP 65

__global__ __launch_bounds__(256)
void gemm_fused_kernel(const ushort_t* __restrict__ xh,
                       const ushort_t* __restrict__ Csm_r, const ushort_t* __restrict__ Csm_i,
                       const float* __restrict__ dr, const float* __restrict__ di,
                       float* __restrict__ part)
{
    __shared__ __align__(16) char lds[GBM * LDP * 4];
    ushort_t* Ash = (ushort_t*)lds;            // 128*40 halves
    ushort_t* Bsr = Ash + GBM * LDA;           // 64*40
    ushort_t* Bsi = Bsr + GBNC * LDA;          // 64*40
    float*    Ps  = (float*)lds;               // reused after K-loop
    __shared__ float drs[GBNC], dis[GBNC];

    const int tid = threadIdx.x;
    const int bm = blockIdx.x, bn = blockIdx.y;
    const int lane = tid & 63, wv = tid >> 6;
    const int n0 = bn * GBNC;

    if (tid < GBNC) { drs[tid] = dr[n0 + tid]; dis[tid] = di[n0 + tid]; }

    float4v accr[2][4], acci[2][4];
#pragma unroll
    for (int a = 0; a < 2; ++a)
#pragma unroll
        for (int b = 0; b < 4; ++b) { accr[a][b] = (float4v)0.f; acci[a][b] = (float4v)0.f; }

    const int sr = tid >> 1, ko = (tid & 1) * 16;
    const ushort_t* xa = xh + (size_t)(bm * GBM + sr) * SEQ + ko;
    const int bsel = tid >> 7;
    const int nr = (tid & 127) >> 1;
    const int bko = (tid & 1) * 16;
    const ushort_t* bsrc = (bsel ? Csm_i : Csm_r) + (size_t)(n0 + nr) * SEQ + bko;
    ushort_t* bdst = (bsel ? Bsi : Bsr) + nr * LDA + bko;

    const int fm = lane & 15, kq = (lane >> 4) * 8;
    const int wrow = wv * 32;

    for (int k0 = 0; k0 < SEQ; k0 += GBK) {
        uint4 a0 = *(const uint4*)(xa + k0);
        uint4 a1 = *(const uint4*)(xa + k0 + 8);
        *(uint4*)(Ash + sr * LDA + ko)     = a0;
        *(uint4*)(Ash + sr * LDA + ko + 8) = a1;
        uint4 b0 = *(const uint4*)(bsrc + k0);
        uint4 b1 = *(const uint4*)(bsrc + k0 + 8);
        *(uint4*)bdst       = b0;
        *(uint4*)(bdst + 8) = b1;
        __syncthreads();

        half8 ah0 = *(half8*)(Ash + (wrow + fm) * LDA + kq);
        half8 ah1 = *(half8*)(Ash + (wrow + 16 + fm) * LDA + kq);
#pragma unroll
        for (int nt = 0; nt < 4; ++nt) {
            half8 br = *(half8*)(Bsr + (nt * 16 + fm) * LDA + kq);
            half8 bi = *(half8*)(Bsi + (nt * 16 + fm) * LDA + kq);
            accr[0][nt] = __builtin_amdgcn_mfma_f32_16x16x32_f16(ah0, br, accr[0][nt], 0, 0, 0);
            accr[1][nt] = __builtin_amdgcn_mfma_f32_16x16x32_f16(ah1, br, accr[1][nt], 0, 0, 0);
            acci[0][nt] = __builtin_amdgcn_mfma_f32_16x16x32_f16(ah0, bi, acci[0][nt], 0, 0, 0);
            acci[1][nt] = __builtin_amdgcn_mfma_f32_16x16x32_f16(ah1, bi, acci[1][nt], 0, 0, 0);
        }
        __syncthreads();
    }

    const int rq = (lane >> 4) * 4;
#pragma unroll
    for (int mt = 0; mt < 2; ++mt)
#pragma unroll
        for (int nt = 0; nt < 4; ++nt) {
            float drv = drs[nt * 16 + fm], div = dis[nt * 16 + fm];
#pragma unroll
            for (int reg = 0; reg < 4; ++reg) {
                int lrow = wrow + mt * 16 + rq + reg;
                float zr = accr[mt][nt][reg] + drv;
                float zi = acci[mt][nt][reg] + div;
                Ps[lrow * LDP + nt * 16 + fm] = zr * zr + zi * zi;
            }
        }
    __syncthreads();

    {
        const int row = tid >> 1, hh = tid & 1;
        const float* pr = Ps + row * LDP + hh * 32;
        float nrm = 0.f, e0 = 0.f, e1 = 0.f, e2 = 0.f, e3 = 0.f, e4 = 0.f, e5 = 0.f;
#pragma unroll
        for (int i = 0; i < 32; ++i) {
            float p = pr[i];
            int c = hh * 32 + i;
            nrm += p;
            e0 += ((c >> 5) & 1) ? -p : p;
            e1 += ((c >> 4) & 1) ? -p : p;
            e2 += ((c >> 3) & 1) ? -p : p;
            e3 += ((c >> 2) & 1) ? -p : p;
            e4 += ((c >> 1) & 1) ? -p : p;
            e5 += (c & 1) ? -p : p;
        }
        size_t base = ((size_t)(bm * GBM + row) * 32 + (bn * 2 + hh)) * 8;
        part[base + 0] = nrm;
        part[base + 1] = e0; part[base + 2] = e1; part[base + 3] = e2;
        part[base + 4] = e3; part[base + 5] = e4; part[base + 6] = e5;
    }
}

// ---------------------------------------------------------------------------
// Kernel 4: per-row wave-parallel combine + W_out epilogue.
// ---------------------------------------------------------------------------
__global__ __launch_bounds__(128)
void finalize_kernel(const float* __restrict__ part, const float* __restrict__ W_out,
                     const float* __restrict__ b_out, float* __restrict__ out)
{
    __shared__ float evf[16];
    const int row = blockIdx.x, tid = threadIdx.x;

    if (tid < 64) {
        float v[11];
        if (tid < 32) {
            const float* p = part + ((size_t)row * 32 + tid) * 8;
            float4 a = *(const float4*)p;
            float4 b = *(const float4*)(p + 4);
            float nrm = a.x;
            int bnn = tid >> 1;
            v[0] = nrm;
            v[1] = (bnn & 8) ? -nrm : nrm;
            v[2] = (bnn & 4) ? -nrm : nrm;
            v[3] = (bnn & 2) ? -nrm : nrm;
            v[4] = (bnn & 1) ? -nrm : nrm;
            v[5] = a.y; v[6] = a.z; v[7] = a.w;
            v[8] = b.x; v[9] = b.y; v[10] = b.z;
        } else {
#pragma unroll
            for (int k = 0; k < 11; ++k) v[k] = 0.f;
        }
#pragma unroll
        for (int m = 16; m; m >>= 1)
#pragma unroll
            for (int k = 0; k < 11; ++k) v[k] += __shfl_xor(v[k], m, 64);
        if (tid == 0) {
            float inv = 1.0f / v[0];
#pragma unroll
            for (int k = 0; k < 10; ++k) evf[k] = v[k + 1] * inv;
        }
    }
    __syncthreads();
    if (tid < PRED) {
        float o = b_out[tid];
#pragma unroll
        for (int k = 0; k < NQ; ++k) o = fmaf(W_out[tid * NQ + k], evf[k], o);
        out[(size_t)row * PRED + tid] = o;
    }
}

extern "C" void kernel_launch(void* const* d_in, const int* in_sizes, int n_in,
                              void* d_out, int out_size, void* d_ws, size_t ws_size,
                              hipStream_t stream) {
    const float* x     = (const float*)d_in[0];
    const float* W_in  = (const float*)d_in[1];
    const float* b_in  = (const float*)d_in[2];
    const float* qw    = (const float*)d_in[3];
    const float* W_out = (const float*)d_in[4];
    const float* b_out = (const float*)d_in[5];
    float* out = (float*)d_out;

    char* w = (char*)d_ws;
    const size_t MB = 1u << 20;
    ushort_t* xh    = (ushort_t*)w;               // 4 MB
    ushort_t* Cjm_r = (ushort_t*)(w + 4 * MB);    // 1 MB  [j][s]
    ushort_t* Cjm_i = (ushort_t*)(w + 5 * MB);    // 1 MB
    ushort_t* Csm_r = (ushort_t*)(w + 6 * MB);    // 1 MB  [s][j]
    ushort_t* Csm_i = (ushort_t*)(w + 7 * MB);    // 1 MB
    float*    dr    = (float*)(w + 8 * MB);       // 4 KB
    float*    di    = dr + DIM;                   // 4 KB
    float*    part  = (float*)(w + 9 * MB);       // 4 MB

    convert_x_kernel<<<NROWS * SEQ / (256 * 8), 256, 0, stream>>>(x, xh);
    circuit_wave_kernel<<<129, 256, 0, stream>>>(W_in, b_in, qw, Cjm_r, Cjm_i, dr, di);
    transpose_c_kernel<<<dim3(SEQ / 64, DIM / 64), 256, 0, stream>>>(Cjm_r, Cjm_i, Csm_r, Csm_i);
    dim3 g2(NROWS / GBM, DIM / GBNC);
    gemm_fused_kernel<<<g2, 256, 0, stream>>>(xh, Csm_r, Csm_i, dr, di, part);
    finalize_kernel<<<NROWS, 128, 0, stream>>>(part, W_out, b_out, out);
}